// Round 11
// baseline (131.077 us; speedup 1.0000x reference)
//
#include <hip/hip_runtime.h>
#include <math.h>

// Converse2D (USRNet closed-form prox), s=2, B=4, C=64, H=W=128, K=5.
// Two dispatches: precompute_K (v4, R8-verified) + converse_main.
//
// R1-R8: coalesced K stores; LDS-only barriers; spill elimination by register-
//   demand reduction (WRITE exactly 64MiB); precompute LDS P-staging + algebra
//   compression. R8 best clean baseline: converse 52us, WRITE 65536 exact.
// R9 (rejected): single-dispatch fusion -> spills+conflicts; proved the ~60us
//   total-vs-kernel gap is harness overhead. Objective = sum of kernel times.
// R10: radix-8/16 phase deepening, barriers 21->16: 49.8us BUT reintroduced
//   spill (WRITE 78848, FETCH 23.2MB): inv_oct's fully-unrolled 2-iteration
//   loop keeps 2x f[8] = 32 live regs interleaved, which in pass 0 coexists
//   with sA(16)+sB(10) > 64 budget. Forward/pass-1 octets have no sA/sB ->
//   clean. LDS-parking is maxed (157KB/160KB).
// R11: serialize the octet iterations (#pragma unroll 1) -> peak f-state 16
//   regs; pass-0 inverse fits the 64-VGPR budget again. Cross-wave TLP (16
//   waves/CU) covers the lost intra-thread ILP.

struct cx { float x, y; };
__device__ __forceinline__ cx cmul(cx a, cx b){ return cx{a.x*b.x - a.y*b.y, a.x*b.y + a.y*b.x}; }
__device__ __forceinline__ cx cadd(cx a, cx b){ return cx{a.x+b.x, a.y+b.y}; }
__device__ __forceinline__ cx csub(cx a, cx b){ return cx{a.x-b.x, a.y-b.y}; }
__device__ __forceinline__ cx cconj(cx a){ return cx{a.x, -a.y}; }

__device__ __forceinline__ float2 cmulf(float2 a, float2 b){
    return make_float2(a.x*b.x - a.y*b.y, a.x*b.y + a.y*b.x);
}
__device__ __forceinline__ float2 cmulcf(float2 a, float2 b){ // a * conj(b)
    return make_float2(a.x*b.x + a.y*b.y, a.y*b.x - a.x*b.y);
}
__device__ __forceinline__ float2 caddf(float2 a, float2 b){ return make_float2(a.x+b.x, a.y+b.y); }
__device__ __forceinline__ float2 csubf(float2 a, float2 b){ return make_float2(a.x-b.x, a.y-b.y); }

// conj(w)*A + w*B  (conjugate-symmetric pair term of the 5-tap DFT)
__device__ __forceinline__ cx conjpair(cx w, float2 A, float2 B){
    return cx{ w.x*(A.x+B.x) + w.y*(A.y-B.y),
               w.x*(A.y+B.y) - w.y*(A.x-B.x) };
}

// LDS-only barrier: waits ds ops, leaves global loads/stores in flight.
__device__ __forceinline__ void barrier_lds(){
    __builtin_amdgcn_sched_barrier(0);
    asm volatile("s_waitcnt lgkmcnt(0)" ::: "memory");
    __builtin_amdgcn_s_barrier();
    __builtin_amdgcn_sched_barrier(0);
}

// ---------------- precompute_K v4 (R8-verified): LDS P-staging + compressed algebra ----
// Grid: 2048 blocks = 64 channels x 32 slabs (512 output points each).
__global__ __launch_bounds__(256)
void precompute_K(const float* __restrict__ weight, const float* __restrict__ lam_ptr,
                  float2* __restrict__ KA, float2* __restrict__ KB)
{
    __shared__ float2 P[5 * 256];      // P[a][rot(R)], R in [0,256)

    const int tid  = threadIdx.x;
    const int c    = blockIdx.x >> 5;  // channel
    const int slab = blockIdx.x & 31;  // 512-point slab of the 16384-pt table

    const float* wc = weight + c*25;   // wave-uniform -> scalar loads
    const float lam = lam_ptr[0];
    const float inv_lam = 1.0f / lam;
    const float th  = -6.28318530717958647692f * (1.0f/256.0f);

    {
        float s1,c1, s2,c2;
        __sincosf(th * (float)tid,     &s1, &c1);
        __sincosf(th * (float)(2*tid), &s2, &c2);
        cx er[5] = { cx{c2,-s2}, cx{c1,-s1}, cx{1.f,0.f}, cx{c1,s1}, cx{c2,s2} };
        const int rs = (tid >> 1) | ((tid & 1) << 7);   // rot(R)
        #pragma unroll
        for (int a = 0; a < 5; ++a) {
            float px = 0.f, py = 0.f;
            #pragma unroll
            for (int b = 0; b < 5; ++b) {
                float w = wc[a*5 + b];
                px += w * er[b].x;
                py += w * er[b].y;
            }
            P[a*256 + rs] = make_float2(px, py);
        }
    }
    __syncthreads();

    const float scale = 1.0f / 65536.0f;

    #pragma unroll 1
    for (int it = 0; it < 2; ++it) {
        const int p  = slab*512 + it*256 + tid;
        const int qb = p >> 7, rb = p & 127;
        const int q = (int)(__brev((unsigned)qb) >> 25);
        const int r = (int)(__brev((unsigned)rb) >> 25);
        const int rr = (r >> 1) | ((r & 1) << 7);

        float sq1,cq1, sq2,cq2, sr1,cr1;
        __sincosf(th * (float)q,     &sq1, &cq1);
        __sincosf(th * (float)(2*q), &sq2, &cq2);
        __sincosf(th * (float)r,     &sr1, &cr1);
        const cx w1{cq1, sq1};
        const cx w2{cq2, sq2};
        const cx wr{cr1, sr1};

        float2 p0_0 = P[0*256+rr], p1_0 = P[0*256+rr+64];
        float2 p0_1 = P[1*256+rr], p1_1 = P[1*256+rr+64];
        float2 p0_2 = P[2*256+rr], p1_2 = P[2*256+rr+64];
        float2 p0_3 = P[3*256+rr], p1_3 = P[3*256+rr+64];
        float2 p0_4 = P[4*256+rr], p1_4 = P[4*256+rr+64];
        cx B1 = conjpair(w1, p0_1, p0_3);
        cx B2 = conjpair(w2, p0_0, p0_4);
        cx m0 = cx{p0_2.x, p0_2.y};
        cx F00 = cadd(cadd(m0, B1), B2);
        cx F10 = cadd(csub(m0, B1), B2);
        cx D1 = conjpair(w1, p1_1, p1_3);
        cx D2 = conjpair(w2, p1_0, p1_4);
        cx m1 = cx{p1_2.x, p1_2.y};
        cx F01 = cadd(cadd(m1, D1), D2);
        cx F11 = cadd(csub(m1, D1), D2);

        float SF2 = F00.x*F00.x + F00.y*F00.y + F01.x*F01.x + F01.y*F01.y
                  + F10.x*F10.x + F10.y*F10.y + F11.x*F11.x + F11.y*F11.y;
        cx Du0{1.f+cq1,  sq1}, Du1{1.f-cq1, -sq1};
        cx Dv0{1.f+cr1,  sr1}, Dv1{1.f-cr1, -sr1};
        cx T = cadd(cmul(Du0, cadd(cmul(F00,Dv0), cmul(F01,Dv1))),
                    cmul(Du1, cadd(cmul(F10,Dv0), cmul(F11,Dv1))));
        float invW = 0.25f * SF2;
        cx M{invW + 0.25f*lam*T.x, 0.25f*lam*T.y};
        float idn = 1.0f / (invW + lam);
        cx V{M.x*idn, M.y*idn};
        cx W{(1.f - V.x)*inv_lam, -V.y*inv_lam};

        cx Sa = cadd(F00,F01), Sb = cadd(F10,F11);
        cx Da = csub(F00,F01), Db = csub(F10,F11);
        cx C00 = cadd(Sa,Sb), C10 = csub(Sa,Sb);
        cx C01 = cadd(Da,Db), C11 = csub(Da,Db);

        cx WR  = cmul(W,  cconj(wr));
        cx WQ  = cmul(W,  cconj(w1));
        cx WQR = cmul(WQ, cconj(wr));
        cx H0 = cadd(cmul(cconj(C00), W  ), cx{4.f,0.f});
        cx H1 = cadd(cmul(cconj(C01), WR ), cx{4.f,0.f});
        cx H2 = cadd(cmul(cconj(C10), WQ ), cx{4.f,0.f});
        cx H3 = cadd(cmul(cconj(C11), WQR), cx{4.f,0.f});

        float2 kAv = make_float2((H0.x - H1.y)*scale, (H0.y + H1.x)*scale);
        float2 kBv = make_float2((H2.x - H3.y)*scale, (H2.y + H3.x)*scale);
        const int o = (c << 14) + p;
        KA[o] = kAv;
        KB[o] = kBv;
    }
}

#define ST2 129   // float2 stride: odd -> both row & col passes at bank-bandwidth minimum

template<int AXIS> __device__ __forceinline__ int laddr(int line, int i){
    return AXIS ? (i*ST2 + line) : (line*ST2 + i);
}

// ---- Forward DIF radix-8: fused stages S, S+1, S+2 (S in {0,3}). ----
// 2048 octets, 2/thread, iterations SERIAL (16 live f-regs, not 32).
template<int AXIS, int S>
__device__ __forceinline__ void fwd_oct(float2* Sm, const float2* TW, int tid)
{
    const int hhh = 16 >> S;               // element stride within octet
    #pragma unroll 1
    for (int it = 0; it < 2; ++it) {
        int qid  = it*1024 + tid;
        int line = qid & 127;
        int t    = qid >> 7;               // [0,16)
        int j    = t & (hhh - 1);
        int blk  = t >> (4 - S);
        int i0   = (blk << (7 - S)) + j;
        float2 f[8];
        #pragma unroll
        for (int k = 0; k < 8; ++k) f[k] = Sm[laddr<AXIS>(line, i0 + k*hhh)];
        // stage S (span 4*hhh): pairs (k, k+4), tw TW[(j<<S) + k*16]
        #pragma unroll
        for (int k = 0; k < 4; ++k) {
            float2 a = f[k], b = f[k+4];
            f[k]   = caddf(a, b);
            f[k+4] = cmulf(csubf(a, b), TW[(j << S) + k*16]);
        }
        // stage S+1 (span 2*hhh): pairs (k,k+2) per half, tw TW[(j<<(S+1)) + k*32]
        #pragma unroll
        for (int h8 = 0; h8 < 8; h8 += 4)
          #pragma unroll
          for (int k = 0; k < 2; ++k) {
            float2 a = f[h8+k], b = f[h8+k+2];
            f[h8+k]   = caddf(a, b);
            f[h8+k+2] = cmulf(csubf(a, b), TW[(j << (S+1)) + k*32]);
          }
        // stage S+2 (span hhh): pairs (k,k+1), tw TW[j<<(S+2)] (same all pairs)
        float2 wC = TW[j << (S+2)];
        #pragma unroll
        for (int h4 = 0; h4 < 8; h4 += 2) {
            float2 a = f[h4], b = f[h4+1];
            f[h4]   = caddf(a, b);
            f[h4+1] = cmulf(csubf(a, b), wC);
        }
        #pragma unroll
        for (int k = 0; k < 8; ++k) Sm[laddr<AXIS>(line, i0 + k*hhh)] = f[k];
    }
}

// ---- Forward DIF radix-16: fused row stages 3,4,5,6. 1024 groups, 1/thread. ----
template<int AXIS>
__device__ __forceinline__ void fwd_oct16(float2* Sm, const float2* TW, int tid)
{
    int line = tid & 127;
    int g    = tid >> 7;                   // [0,8)
    int i0   = g * 16;
    float2 f[16];
    #pragma unroll
    for (int k = 0; k < 16; ++k) f[k] = Sm[laddr<AXIS>(line, i0 + k)];
    // stage 3 (span 8): pairs (k,k+8), tw TW[k<<3]
    #pragma unroll
    for (int k = 0; k < 8; ++k) {
        float2 a = f[k], b = f[k+8];
        f[k]   = caddf(a, b);
        f[k+8] = cmulf(csubf(a, b), TW[k << 3]);
    }
    // stage 4 (span 4): pairs (k,k+4) per 8, tw TW[(k&3)<<4]
    #pragma unroll
    for (int h = 0; h < 16; h += 8)
      #pragma unroll
      for (int k = 0; k < 4; ++k) {
        float2 a = f[h+k], b = f[h+k+4];
        f[h+k]   = caddf(a, b);
        f[h+k+4] = cmulf(csubf(a, b), TW[k << 4]);
      }
    // stage 5 (span 2): pairs (k,k+2) per 4, tw TW[(k&1)<<5]
    #pragma unroll
    for (int h = 0; h < 16; h += 4)
      #pragma unroll
      for (int k = 0; k < 2; ++k) {
        float2 a = f[h+k], b = f[h+k+2];
        f[h+k]   = caddf(a, b);
        f[h+k+2] = cmulf(csubf(a, b), TW[k << 5]);
      }
    // stage 6 (span 1): pairs (k,k+1), tw 1
    #pragma unroll
    for (int h = 0; h < 16; h += 2) {
        float2 a = f[h], b = f[h+1];
        f[h]   = caddf(a, b);
        f[h+1] = csubf(a, b);
    }
    #pragma unroll
    for (int k = 0; k < 16; ++k) Sm[laddr<AXIS>(line, i0 + k)] = f[k];
}

// ---- Inverse DIT radix-8: fused stages S, S+1, S+2 (conj twiddles). ----
// Iterations SERIAL: peak f-state 16 regs so pass-0 (sA/sB live) fits 64 VGPRs.
template<int AXIS, int S>
__device__ __forceinline__ void inv_oct(float2* Sm, const float2* TW, int tid)
{
    const int h = 1 << S;
    #pragma unroll 1
    for (int it = 0; it < 2; ++it) {
        int qid  = it*1024 + tid;
        int line = qid & 127;
        int t    = qid >> 7;
        int j    = t & (h - 1);
        int blk  = t >> S;
        int base = (blk << (S + 3)) + j;
        float2 f[8];
        #pragma unroll
        for (int k = 0; k < 8; ++k) f[k] = Sm[laddr<AXIS>(line, base + k*h)];
        // stage S: pairs (2i, 2i+1), tw cwA = TW[j<<(6-S)]
        float2 cwA = TW[j << (6 - S)];
        #pragma unroll
        for (int i = 0; i < 4; ++i) {
            float2 a = f[2*i], b = cmulcf(f[2*i+1], cwA);
            f[2*i]   = caddf(a, b);
            f[2*i+1] = csubf(a, b);
        }
        // stage S+1: pairs (i, i+2) per half; tw TW[j<<(5-S)] / +32
        float2 cwB0 = TW[j << (5 - S)];
        float2 cwB1 = TW[(j << (5 - S)) + 32];
        #pragma unroll
        for (int hb = 0; hb < 8; hb += 4) {
            float2 u = cmulcf(f[hb+2], cwB0);
            float2 a0 = f[hb+0];
            f[hb+0] = caddf(a0, u);
            f[hb+2] = csubf(a0, u);
            float2 v = cmulcf(f[hb+3], cwB1);
            float2 a1 = f[hb+1];
            f[hb+1] = caddf(a1, v);
            f[hb+3] = csubf(a1, v);
        }
        // stage S+2: pairs (k, k+4); tw TW[(j<<(4-S)) + k*16]
        #pragma unroll
        for (int k = 0; k < 4; ++k) {
            float2 w = cmulcf(f[k+4], TW[(j << (4 - S)) + k*16]);
            float2 a = f[k];
            f[k]   = caddf(a, w);
            f[k+4] = csubf(a, w);
        }
        #pragma unroll
        for (int k = 0; k < 8; ++k) Sm[laddr<AXIS>(line, base + k*h)] = f[k];
    }
}

__global__ __launch_bounds__(1024)
void converse_main(const float* __restrict__ x, const float* __restrict__ bias,
                   const float2* __restrict__ KA, const float2* __restrict__ KB,
                   float* __restrict__ out)
{
    __shared__ float2 S[128 * ST2];
    __shared__ float2 TW[64];
    __shared__ float2 SB[3 * 1024];   // sB[5..7] parked here (LDS slack, no spill)

    const int tid = threadIdx.x;
    const int bc  = blockIdx.x;       // [0,256) = b*64 + c
    const int c   = bc & 63;

    if (tid < 64) {
        float s_, c_;
        __sincosf(-6.28318530717958647692f * (float)tid * (1.0f/128.0f), &s_, &c_);
        TW[tid] = make_float2(c_, s_);
    }

    // ---- load x[b,c] as {x, 0} (coalesced 4B/lane, conflict-free LDS writes) ----
    const float* xp = x + (size_t)bc * 16384;
    #pragma unroll
    for (int it = 0; it < 16; ++it) {
        int n = it * 1024 + tid;
        S[(n >> 7) * ST2 + (n & 127)] = make_float2(xp[n], 0.0f);
    }
    barrier_lds();

    // ---- forward rows: radix-8 (0-2) + radix-16 (3-6) ----
    fwd_oct<0,0>(S, TW, tid);  barrier_lds();
    fwd_oct16<0>(S, TW, tid);  barrier_lds();

    // ---- forward cols: radix-8 (0-2) + radix-8 (3-5); stage 6 fused in mult ----
    fwd_oct<1,0>(S, TW, tid);  barrier_lds();
    fwd_oct<1,3>(S, TW, tid);  barrier_lds();

    const float bv = bias[c];
    float* op = out + (size_t)bc * 65536;
    const float2* KpA = KA + (size_t)c * 16384;
    const float2* KpB = KB + (size_t)c * 16384;
    const int nn = tid & 127;
    const int t7 = tid >> 7;
    const int kbase = t7*256 + nn;

    // ---- FUSED: forward col stage 6 + spectrum retain + pass-0 K-mult ----
    float2 sA[8], sB[5];
    #pragma unroll
    for (int it = 0; it < 8; ++it) {
        int j = it*8 + t7;
        float2 kA0 = KpA[it*2048 + kbase];
        float2 kA1 = KpA[it*2048 + kbase + 128];
        int a = (2*j)*ST2 + nn;
        float2 u = S[a], v = S[a + ST2];
        float2 vA = caddf(u, v);
        float2 vB = csubf(u, v);
        sA[it] = vA;
        if (it < 5) sB[it] = vB;
        else        SB[(it-5)*1024 + tid] = vB;
        float2 w0 = cmulf(vA, kA0);
        float2 w1 = cmulf(vB, kA1);
        S[a]       = caddf(w0, w1);       // own addresses: no barrier needed
        S[a + ST2] = csubf(w0, w1);
    }
    barrier_lds();

    // ================= pass 0 (KA, even output rows) =================
    inv_oct<1,1>(S, TW, tid); barrier_lds();   // col stages 1-3
    inv_oct<1,4>(S, TW, tid); barrier_lds();   // col stages 4-6
    inv_oct<0,0>(S, TW, tid); barrier_lds();   // row stages 0-2
    inv_oct<0,3>(S, TW, tid); barrier_lds();   // row stages 3-5

    #pragma unroll
    for (int it = 0; it < 8; ++it) {     // inverse row stage 6 fused with store
        int g = it*1024 + tid;
        int j = g & 63, m = g >> 6;
        int a = m*ST2 + j;
        float2 u = S[a], v = S[a + 64];
        float2 t = cmulcf(v, TW[j]);
        float2 o0 = caddf(u, t);
        float2 o1 = csubf(u, t);
        size_t ro = (size_t)(2*m) * 256;
        *(float2*)(op + ro + 2*j)       = make_float2(o0.x + bv, o0.y + bv);
        *(float2*)(op + ro + 2*j + 128) = make_float2(o1.x + bv, o1.y + bv);
    }
    barrier_lds();   // protect S (ds_reads retired); global stores stay in flight

    // ================= pass 1 (KB, odd output rows) =================
    #pragma unroll
    for (int it = 0; it < 8; ++it) {
        int j = it*8 + t7;
        float2 kB0 = KpB[it*2048 + kbase];
        float2 kB1 = KpB[it*2048 + kbase + 128];
        float2 vB = (it < 5) ? sB[it] : SB[(it-5)*1024 + tid];
        float2 w0 = cmulf(sA[it], kB0);
        float2 w1 = cmulf(vB, kB1);
        int a = (2*j)*ST2 + nn;
        S[a]       = caddf(w0, w1);
        S[a + ST2] = csubf(w0, w1);
    }
    barrier_lds();

    inv_oct<1,1>(S, TW, tid); barrier_lds();
    inv_oct<1,4>(S, TW, tid); barrier_lds();
    inv_oct<0,0>(S, TW, tid); barrier_lds();
    inv_oct<0,3>(S, TW, tid); barrier_lds();

    #pragma unroll
    for (int it = 0; it < 8; ++it) {
        int g = it*1024 + tid;
        int j = g & 63, m = g >> 6;
        int a = m*ST2 + j;
        float2 u = S[a], v = S[a + 64];
        float2 t = cmulcf(v, TW[j]);
        float2 o0 = caddf(u, t);
        float2 o1 = csubf(u, t);
        size_t ro = (size_t)(2*m + 1) * 256;
        *(float2*)(op + ro + 2*j)       = make_float2(o0.x + bv, o0.y + bv);
        *(float2*)(op + ro + 2*j + 128) = make_float2(o1.x + bv, o1.y + bv);
    }
}

extern "C" void kernel_launch(void* const* d_in, const int* in_sizes, int n_in,
                              void* d_out, int out_size, void* d_ws, size_t ws_size,
                              hipStream_t stream)
{
    const float* x      = (const float*)d_in[0];   // [4,64,128,128]
    const float* weight = (const float*)d_in[1];   // [1,64,5,5]
    const float* bias   = (const float*)d_in[2];   // [1,64,1,1]
    const float* lam    = (const float*)d_in[3];   // [1,1,1,1]
    float* out = (float*)d_out;                    // [4,64,256,256]

    float2* KA = (float2*)d_ws;                    // 8 MB
    float2* KB = KA + (size_t)64 * 16384;          // 8 MB

    hipLaunchKernelGGL(precompute_K, dim3(2048), dim3(256), 0, stream,
                       weight, lam, KA, KB);
    hipLaunchKernelGGL(converse_main, dim3(256), dim3(1024), 0, stream,
                       x, bias, KA, KB, out);
}

// Round 12
// 124.513 us; speedup vs baseline: 1.0527x; 1.0527x over previous
//
#include <hip/hip_runtime.h>
#include <math.h>

// Converse2D (USRNet closed-form prox), s=2, B=4, C=64, H=W=128, K=5.
// Two dispatches: precompute_K (v4, R8-verified) + converse_main.
//
// R1-R8: coalesced K stores; LDS-only barriers; spill elimination by register-
//   demand reduction; precompute LDS P-staging + algebra compression.
//   R8 clean baseline: radix-4 everywhere, 21 barriers, WRITE exactly 65536.
// R9 (rejected): fusion -> spills+conflicts; proved ~60us total-vs-kernel gap
//   is harness overhead. Objective = sum of kernel times.
// R10/R11: radix-8/16 deepening (16 barriers, ~50us) but pass-0 inverse
//   respilled sB[0..4] (~44B/thread: WRITE 76800, FETCH 22.8MB); unroll-1
//   experiment proved interleaving wasn't the cause -- it's f[8]+sA+sB > 64.
// R12: hybrid radii + fused input load.
//   (a) pass-0 inverse -> radix-4 pairs (f[4], live ~52, R8-proven clean);
//       pass-1 inverse stays radix-8 (sA/sB dead there, no spill).
//   (b) x-load fused into first fwd phase: lanes remapped (j=qid&15,
//       line=qid>>4) so global loads are 16-consecutive-column coalesced,
//       radix-8 stages 0-2 straight from registers (stage-0 imag folds to 0);
//       removes the staging loop + 1 barrier + a full LDS round-trip of x.

struct cx { float x, y; };
__device__ __forceinline__ cx cmul(cx a, cx b){ return cx{a.x*b.x - a.y*b.y, a.x*b.y + a.y*b.x}; }
__device__ __forceinline__ cx cadd(cx a, cx b){ return cx{a.x+b.x, a.y+b.y}; }
__device__ __forceinline__ cx csub(cx a, cx b){ return cx{a.x-b.x, a.y-b.y}; }
__device__ __forceinline__ cx cconj(cx a){ return cx{a.x, -a.y}; }

__device__ __forceinline__ float2 cmulf(float2 a, float2 b){
    return make_float2(a.x*b.x - a.y*b.y, a.x*b.y + a.y*b.x);
}
__device__ __forceinline__ float2 cmulcf(float2 a, float2 b){ // a * conj(b)
    return make_float2(a.x*b.x + a.y*b.y, a.y*b.x - a.x*b.y);
}
__device__ __forceinline__ float2 caddf(float2 a, float2 b){ return make_float2(a.x+b.x, a.y+b.y); }
__device__ __forceinline__ float2 csubf(float2 a, float2 b){ return make_float2(a.x-b.x, a.y-b.y); }

// conj(w)*A + w*B  (conjugate-symmetric pair term of the 5-tap DFT)
__device__ __forceinline__ cx conjpair(cx w, float2 A, float2 B){
    return cx{ w.x*(A.x+B.x) + w.y*(A.y-B.y),
               w.x*(A.y+B.y) - w.y*(A.x-B.x) };
}

// LDS-only barrier: waits ds ops, leaves global loads/stores in flight.
__device__ __forceinline__ void barrier_lds(){
    __builtin_amdgcn_sched_barrier(0);
    asm volatile("s_waitcnt lgkmcnt(0)" ::: "memory");
    __builtin_amdgcn_s_barrier();
    __builtin_amdgcn_sched_barrier(0);
}

// ---------------- precompute_K v4 (R8-verified): LDS P-staging + compressed algebra ----
__global__ __launch_bounds__(256)
void precompute_K(const float* __restrict__ weight, const float* __restrict__ lam_ptr,
                  float2* __restrict__ KA, float2* __restrict__ KB)
{
    __shared__ float2 P[5 * 256];      // P[a][rot(R)], R in [0,256)

    const int tid  = threadIdx.x;
    const int c    = blockIdx.x >> 5;  // channel
    const int slab = blockIdx.x & 31;  // 512-point slab of the 16384-pt table

    const float* wc = weight + c*25;   // wave-uniform -> scalar loads
    const float lam = lam_ptr[0];
    const float inv_lam = 1.0f / lam;
    const float th  = -6.28318530717958647692f * (1.0f/256.0f);

    {
        float s1,c1, s2,c2;
        __sincosf(th * (float)tid,     &s1, &c1);
        __sincosf(th * (float)(2*tid), &s2, &c2);
        cx er[5] = { cx{c2,-s2}, cx{c1,-s1}, cx{1.f,0.f}, cx{c1,s1}, cx{c2,s2} };
        const int rs = (tid >> 1) | ((tid & 1) << 7);   // rot(R)
        #pragma unroll
        for (int a = 0; a < 5; ++a) {
            float px = 0.f, py = 0.f;
            #pragma unroll
            for (int b = 0; b < 5; ++b) {
                float w = wc[a*5 + b];
                px += w * er[b].x;
                py += w * er[b].y;
            }
            P[a*256 + rs] = make_float2(px, py);
        }
    }
    __syncthreads();

    const float scale = 1.0f / 65536.0f;

    #pragma unroll 1
    for (int it = 0; it < 2; ++it) {
        const int p  = slab*512 + it*256 + tid;
        const int qb = p >> 7, rb = p & 127;
        const int q = (int)(__brev((unsigned)qb) >> 25);
        const int r = (int)(__brev((unsigned)rb) >> 25);
        const int rr = (r >> 1) | ((r & 1) << 7);

        float sq1,cq1, sq2,cq2, sr1,cr1;
        __sincosf(th * (float)q,     &sq1, &cq1);
        __sincosf(th * (float)(2*q), &sq2, &cq2);
        __sincosf(th * (float)r,     &sr1, &cr1);
        const cx w1{cq1, sq1};
        const cx w2{cq2, sq2};
        const cx wr{cr1, sr1};

        float2 p0_0 = P[0*256+rr], p1_0 = P[0*256+rr+64];
        float2 p0_1 = P[1*256+rr], p1_1 = P[1*256+rr+64];
        float2 p0_2 = P[2*256+rr], p1_2 = P[2*256+rr+64];
        float2 p0_3 = P[3*256+rr], p1_3 = P[3*256+rr+64];
        float2 p0_4 = P[4*256+rr], p1_4 = P[4*256+rr+64];
        cx B1 = conjpair(w1, p0_1, p0_3);
        cx B2 = conjpair(w2, p0_0, p0_4);
        cx m0 = cx{p0_2.x, p0_2.y};
        cx F00 = cadd(cadd(m0, B1), B2);
        cx F10 = cadd(csub(m0, B1), B2);
        cx D1 = conjpair(w1, p1_1, p1_3);
        cx D2 = conjpair(w2, p1_0, p1_4);
        cx m1 = cx{p1_2.x, p1_2.y};
        cx F01 = cadd(cadd(m1, D1), D2);
        cx F11 = cadd(csub(m1, D1), D2);

        float SF2 = F00.x*F00.x + F00.y*F00.y + F01.x*F01.x + F01.y*F01.y
                  + F10.x*F10.x + F10.y*F10.y + F11.x*F11.x + F11.y*F11.y;
        cx Du0{1.f+cq1,  sq1}, Du1{1.f-cq1, -sq1};
        cx Dv0{1.f+cr1,  sr1}, Dv1{1.f-cr1, -sr1};
        cx T = cadd(cmul(Du0, cadd(cmul(F00,Dv0), cmul(F01,Dv1))),
                    cmul(Du1, cadd(cmul(F10,Dv0), cmul(F11,Dv1))));
        float invW = 0.25f * SF2;
        cx M{invW + 0.25f*lam*T.x, 0.25f*lam*T.y};
        float idn = 1.0f / (invW + lam);
        cx V{M.x*idn, M.y*idn};
        cx W{(1.f - V.x)*inv_lam, -V.y*inv_lam};

        cx Sa = cadd(F00,F01), Sb = cadd(F10,F11);
        cx Da = csub(F00,F01), Db = csub(F10,F11);
        cx C00 = cadd(Sa,Sb), C10 = csub(Sa,Sb);
        cx C01 = cadd(Da,Db), C11 = csub(Da,Db);

        cx WR  = cmul(W,  cconj(wr));
        cx WQ  = cmul(W,  cconj(w1));
        cx WQR = cmul(WQ, cconj(wr));
        cx H0 = cadd(cmul(cconj(C00), W  ), cx{4.f,0.f});
        cx H1 = cadd(cmul(cconj(C01), WR ), cx{4.f,0.f});
        cx H2 = cadd(cmul(cconj(C10), WQ ), cx{4.f,0.f});
        cx H3 = cadd(cmul(cconj(C11), WQR), cx{4.f,0.f});

        float2 kAv = make_float2((H0.x - H1.y)*scale, (H0.y + H1.x)*scale);
        float2 kBv = make_float2((H2.x - H3.y)*scale, (H2.y + H3.x)*scale);
        const int o = (c << 14) + p;
        KA[o] = kAv;
        KB[o] = kBv;
    }
}

#define ST2 129   // float2 stride: odd -> both row & col passes at bank-bandwidth minimum

template<int AXIS> __device__ __forceinline__ int laddr(int line, int i){
    return AXIS ? (i*ST2 + line) : (line*ST2 + i);
}

// ---- Forward radix-8 rows stages 0-2, input DIRECT from global. ----
// Lanes remapped: j = qid&15 (column-of-octet), line = qid>>4 -> 16 consecutive
// lanes read 16 consecutive floats (coalesced). Stage-0 imag is literal 0.
__device__ __forceinline__ void fwd_oct8_rows_g(float2* Sm, const float2* TW,
                                                const float* __restrict__ xp, int tid)
{
    #pragma unroll 1
    for (int it = 0; it < 2; ++it) {
        int qid  = it*1024 + tid;
        int j    = qid & 15;
        int line = qid >> 4;
        float xr[8];
        #pragma unroll
        for (int k = 0; k < 8; ++k) xr[k] = xp[line*128 + j + k*16];
        float2 f[8];
        // stage 0 (span 64): pairs (k, k+4), tw TW[j + k*16]; inputs real
        #pragma unroll
        for (int k = 0; k < 4; ++k) {
            float a = xr[k], b = xr[k+4];
            f[k]   = make_float2(a + b, 0.0f);
            float d = a - b;
            float2 w = TW[j + k*16];
            f[k+4] = make_float2(d * w.x, d * w.y);
        }
        // stage 1 (span 32): pairs (k,k+2) per half, tw TW[(j<<1) + k*32]
        #pragma unroll
        for (int h8 = 0; h8 < 8; h8 += 4)
          #pragma unroll
          for (int k = 0; k < 2; ++k) {
            float2 a = f[h8+k], b = f[h8+k+2];
            f[h8+k]   = caddf(a, b);
            f[h8+k+2] = cmulf(csubf(a, b), TW[(j << 1) + k*32]);
          }
        // stage 2 (span 16): pairs (k,k+1), tw TW[j<<2]
        float2 wC = TW[j << 2];
        #pragma unroll
        for (int h4 = 0; h4 < 8; h4 += 2) {
            float2 a = f[h4], b = f[h4+1];
            f[h4]   = caddf(a, b);
            f[h4+1] = cmulf(csubf(a, b), wC);
        }
        #pragma unroll
        for (int k = 0; k < 8; ++k) Sm[line*ST2 + j + k*16] = f[k];
    }
}

// ---- Forward DIF radix-8: fused stages S, S+1, S+2 (S in {0,3}). ----
template<int AXIS, int S>
__device__ __forceinline__ void fwd_oct(float2* Sm, const float2* TW, int tid)
{
    const int hhh = 16 >> S;               // element stride within octet
    #pragma unroll 1
    for (int it = 0; it < 2; ++it) {
        int qid  = it*1024 + tid;
        int line = qid & 127;
        int t    = qid >> 7;               // [0,16)
        int j    = t & (hhh - 1);
        int blk  = t >> (4 - S);
        int i0   = (blk << (7 - S)) + j;
        float2 f[8];
        #pragma unroll
        for (int k = 0; k < 8; ++k) f[k] = Sm[laddr<AXIS>(line, i0 + k*hhh)];
        #pragma unroll
        for (int k = 0; k < 4; ++k) {
            float2 a = f[k], b = f[k+4];
            f[k]   = caddf(a, b);
            f[k+4] = cmulf(csubf(a, b), TW[(j << S) + k*16]);
        }
        #pragma unroll
        for (int h8 = 0; h8 < 8; h8 += 4)
          #pragma unroll
          for (int k = 0; k < 2; ++k) {
            float2 a = f[h8+k], b = f[h8+k+2];
            f[h8+k]   = caddf(a, b);
            f[h8+k+2] = cmulf(csubf(a, b), TW[(j << (S+1)) + k*32]);
          }
        float2 wC = TW[j << (S+2)];
        #pragma unroll
        for (int h4 = 0; h4 < 8; h4 += 2) {
            float2 a = f[h4], b = f[h4+1];
            f[h4]   = caddf(a, b);
            f[h4+1] = cmulf(csubf(a, b), wC);
        }
        #pragma unroll
        for (int k = 0; k < 8; ++k) Sm[laddr<AXIS>(line, i0 + k*hhh)] = f[k];
    }
}

// ---- Forward DIF radix-16: fused row stages 3,4,5,6. 1024 groups, 1/thread. ----
template<int AXIS>
__device__ __forceinline__ void fwd_oct16(float2* Sm, const float2* TW, int tid)
{
    int line = tid & 127;
    int g    = tid >> 7;                   // [0,8)
    int i0   = g * 16;
    float2 f[16];
    #pragma unroll
    for (int k = 0; k < 16; ++k) f[k] = Sm[laddr<AXIS>(line, i0 + k)];
    #pragma unroll
    for (int k = 0; k < 8; ++k) {
        float2 a = f[k], b = f[k+8];
        f[k]   = caddf(a, b);
        f[k+8] = cmulf(csubf(a, b), TW[k << 3]);
    }
    #pragma unroll
    for (int h = 0; h < 16; h += 8)
      #pragma unroll
      for (int k = 0; k < 4; ++k) {
        float2 a = f[h+k], b = f[h+k+4];
        f[h+k]   = caddf(a, b);
        f[h+k+4] = cmulf(csubf(a, b), TW[k << 4]);
      }
    #pragma unroll
    for (int h = 0; h < 16; h += 4)
      #pragma unroll
      for (int k = 0; k < 2; ++k) {
        float2 a = f[h+k], b = f[h+k+2];
        f[h+k]   = caddf(a, b);
        f[h+k+2] = cmulf(csubf(a, b), TW[k << 5]);
      }
    #pragma unroll
    for (int h = 0; h < 16; h += 2) {
        float2 a = f[h], b = f[h+1];
        f[h]   = caddf(a, b);
        f[h+1] = csubf(a, b);
    }
    #pragma unroll
    for (int k = 0; k < 16; ++k) Sm[laddr<AXIS>(line, i0 + k)] = f[k];
}

// ---- Inverse DIT radix-4 pair: fused stages (S, S+1) (R8-proven, f[4]=8 regs,
// safe with sA/sB live in pass 0). ----
template<int AXIS, int S>
__device__ __forceinline__ void inv_pair(float2* Sm, const float2* TW, int tid)
{
    const int h = 1 << S;
    #pragma unroll 1
    for (int it = 0; it < 4; ++it) {
        int qid  = it*1024 + tid;
        int line = qid & 127;
        int t    = qid >> 7;
        int blk  = t >> S;
        int j    = t & (h - 1);
        int base = (blk << (S + 2)) + j;
        int a0 = laddr<AXIS>(line, base);
        int a1 = laddr<AXIS>(line, base + h);
        int a2 = laddr<AXIS>(line, base + 2*h);
        int a3 = laddr<AXIS>(line, base + 3*h);
        float2 e0 = Sm[a0], e1 = Sm[a1], e2 = Sm[a2], e3 = Sm[a3];
        float2 cw0 = TW[j << (6 - S)];
        float2 cw1 = TW[j << (5 - S)];
        float2 cw2 = TW[(j << (5 - S)) + 32];
        float2 t1 = cmulcf(e1, cw0);
        float2 A0 = caddf(e0, t1), A1 = csubf(e0, t1);
        float2 t2 = cmulcf(e3, cw0);
        float2 A2 = caddf(e2, t2), A3 = csubf(e2, t2);
        float2 u = cmulcf(A2, cw1);
        Sm[a0] = caddf(A0, u);
        Sm[a2] = csubf(A0, u);
        float2 v = cmulcf(A3, cw2);
        Sm[a1] = caddf(A1, v);
        Sm[a3] = csubf(A1, v);
    }
}

// ---- Inverse DIT radix-8: fused stages S, S+1, S+2 (pass-1 only: sA/sB dead). ----
template<int AXIS, int S>
__device__ __forceinline__ void inv_oct(float2* Sm, const float2* TW, int tid)
{
    const int h = 1 << S;
    #pragma unroll 1
    for (int it = 0; it < 2; ++it) {
        int qid  = it*1024 + tid;
        int line = qid & 127;
        int t    = qid >> 7;
        int j    = t & (h - 1);
        int blk  = t >> S;
        int base = (blk << (S + 3)) + j;
        float2 f[8];
        #pragma unroll
        for (int k = 0; k < 8; ++k) f[k] = Sm[laddr<AXIS>(line, base + k*h)];
        float2 cwA = TW[j << (6 - S)];
        #pragma unroll
        for (int i = 0; i < 4; ++i) {
            float2 a = f[2*i], b = cmulcf(f[2*i+1], cwA);
            f[2*i]   = caddf(a, b);
            f[2*i+1] = csubf(a, b);
        }
        float2 cwB0 = TW[j << (5 - S)];
        float2 cwB1 = TW[(j << (5 - S)) + 32];
        #pragma unroll
        for (int hb = 0; hb < 8; hb += 4) {
            float2 u = cmulcf(f[hb+2], cwB0);
            float2 a0 = f[hb+0];
            f[hb+0] = caddf(a0, u);
            f[hb+2] = csubf(a0, u);
            float2 v = cmulcf(f[hb+3], cwB1);
            float2 a1 = f[hb+1];
            f[hb+1] = caddf(a1, v);
            f[hb+3] = csubf(a1, v);
        }
        #pragma unroll
        for (int k = 0; k < 4; ++k) {
            float2 w = cmulcf(f[k+4], TW[(j << (4 - S)) + k*16]);
            float2 a = f[k];
            f[k]   = caddf(a, w);
            f[k+4] = csubf(a, w);
        }
        #pragma unroll
        for (int k = 0; k < 8; ++k) Sm[laddr<AXIS>(line, base + k*h)] = f[k];
    }
}

__global__ __launch_bounds__(1024)
void converse_main(const float* __restrict__ x, const float* __restrict__ bias,
                   const float2* __restrict__ KA, const float2* __restrict__ KB,
                   float* __restrict__ out)
{
    __shared__ float2 S[128 * ST2];
    __shared__ float2 TW[64];
    __shared__ float2 SB[3 * 1024];   // sB[5..7] parked here (LDS slack)

    const int tid = threadIdx.x;
    const int bc  = blockIdx.x;       // [0,256) = b*64 + c
    const int c   = bc & 63;

    if (tid < 64) {
        float s_, c_;
        __sincosf(-6.28318530717958647692f * (float)tid * (1.0f/128.0f), &s_, &c_);
        TW[tid] = make_float2(c_, s_);
    }
    // TW must be visible before fwd_oct8_rows_g uses it (wave 0 writes it;
    // other waves may race ahead) -> one barrier, which also replaces the old
    // post-staging barrier (staging loop is gone).
    barrier_lds();

    // ---- forward rows: stages 0-2 DIRECT from global (no staging), 3-6 radix-16 ----
    const float* xp = x + (size_t)bc * 16384;
    fwd_oct8_rows_g(S, TW, xp, tid);  barrier_lds();
    fwd_oct16<0>(S, TW, tid);         barrier_lds();

    // ---- forward cols: radix-8 (0-2) + radix-8 (3-5); stage 6 fused in mult ----
    fwd_oct<1,0>(S, TW, tid);  barrier_lds();
    fwd_oct<1,3>(S, TW, tid);  barrier_lds();

    const float bv = bias[c];
    float* op = out + (size_t)bc * 65536;
    const float2* KpA = KA + (size_t)c * 16384;
    const float2* KpB = KB + (size_t)c * 16384;
    const int nn = tid & 127;
    const int t7 = tid >> 7;
    const int kbase = t7*256 + nn;

    // ---- FUSED: forward col stage 6 + spectrum retain + pass-0 K-mult ----
    float2 sA[8], sB[5];
    #pragma unroll
    for (int it = 0; it < 8; ++it) {
        int j = it*8 + t7;
        float2 kA0 = KpA[it*2048 + kbase];
        float2 kA1 = KpA[it*2048 + kbase + 128];
        int a = (2*j)*ST2 + nn;
        float2 u = S[a], v = S[a + ST2];
        float2 vA = caddf(u, v);
        float2 vB = csubf(u, v);
        sA[it] = vA;
        if (it < 5) sB[it] = vB;
        else        SB[(it-5)*1024 + tid] = vB;
        float2 w0 = cmulf(vA, kA0);
        float2 w1 = cmulf(vB, kA1);
        S[a]       = caddf(w0, w1);       // own addresses: no barrier needed
        S[a + ST2] = csubf(w0, w1);
    }
    barrier_lds();

    // ================= pass 0 (KA, even output rows): radix-4, no spill ======
    inv_pair<1,1>(S, TW, tid); barrier_lds();
    inv_pair<1,3>(S, TW, tid); barrier_lds();
    inv_pair<1,5>(S, TW, tid); barrier_lds();
    inv_pair<0,0>(S, TW, tid); barrier_lds();
    inv_pair<0,2>(S, TW, tid); barrier_lds();
    inv_pair<0,4>(S, TW, tid); barrier_lds();

    #pragma unroll
    for (int it = 0; it < 8; ++it) {     // inverse row stage 6 fused with store
        int g = it*1024 + tid;
        int j = g & 63, m = g >> 6;
        int a = m*ST2 + j;
        float2 u = S[a], v = S[a + 64];
        float2 t = cmulcf(v, TW[j]);
        float2 o0 = caddf(u, t);
        float2 o1 = csubf(u, t);
        size_t ro = (size_t)(2*m) * 256;
        *(float2*)(op + ro + 2*j)       = make_float2(o0.x + bv, o0.y + bv);
        *(float2*)(op + ro + 2*j + 128) = make_float2(o1.x + bv, o1.y + bv);
    }
    barrier_lds();   // protect S (ds_reads retired); global stores stay in flight

    // ================= pass 1 (KB, odd output rows): radix-8 (sA/sB die here) ====
    #pragma unroll
    for (int it = 0; it < 8; ++it) {
        int j = it*8 + t7;
        float2 kB0 = KpB[it*2048 + kbase];
        float2 kB1 = KpB[it*2048 + kbase + 128];
        float2 vB = (it < 5) ? sB[it] : SB[(it-5)*1024 + tid];
        float2 w0 = cmulf(sA[it], kB0);
        float2 w1 = cmulf(vB, kB1);
        int a = (2*j)*ST2 + nn;
        S[a]       = caddf(w0, w1);
        S[a + ST2] = csubf(w0, w1);
    }
    barrier_lds();

    inv_oct<1,1>(S, TW, tid); barrier_lds();
    inv_oct<1,4>(S, TW, tid); barrier_lds();
    inv_oct<0,0>(S, TW, tid); barrier_lds();
    inv_oct<0,3>(S, TW, tid); barrier_lds();

    #pragma unroll
    for (int it = 0; it < 8; ++it) {
        int g = it*1024 + tid;
        int j = g & 63, m = g >> 6;
        int a = m*ST2 + j;
        float2 u = S[a], v = S[a + 64];
        float2 t = cmulcf(v, TW[j]);
        float2 o0 = caddf(u, t);
        float2 o1 = csubf(u, t);
        size_t ro = (size_t)(2*m + 1) * 256;
        *(float2*)(op + ro + 2*j)       = make_float2(o0.x + bv, o0.y + bv);
        *(float2*)(op + ro + 2*j + 128) = make_float2(o1.x + bv, o1.y + bv);
    }
}

extern "C" void kernel_launch(void* const* d_in, const int* in_sizes, int n_in,
                              void* d_out, int out_size, void* d_ws, size_t ws_size,
                              hipStream_t stream)
{
    const float* x      = (const float*)d_in[0];   // [4,64,128,128]
    const float* weight = (const float*)d_in[1];   // [1,64,5,5]
    const float* bias   = (const float*)d_in[2];   // [1,64,1,1]
    const float* lam    = (const float*)d_in[3];   // [1,1,1,1]
    float* out = (float*)d_out;                    // [4,64,256,256]

    float2* KA = (float2*)d_ws;                    // 8 MB
    float2* KB = KA + (size_t)64 * 16384;          // 8 MB

    hipLaunchKernelGGL(precompute_K, dim3(2048), dim3(256), 0, stream,
                       weight, lam, KA, KB);
    hipLaunchKernelGGL(converse_main, dim3(256), dim3(1024), 0, stream,
                       x, bias, KA, KB, out);
}